// Round 1
// baseline (862.987 us; speedup 1.0000x reference)
//
#include <hip/hip_runtime.h>
#include <hip/hip_bf16.h>
#include <math.h>

#define NB 4
#define HEADS 8
#define DIM 512
#define MLP 2048
#define NT 2048
#define DH 64
#define M_TOK (NB*NT)

typedef __bf16 bf16;
typedef __bf16 bf16x4 __attribute__((ext_vector_type(4)));
typedef __bf16 bf16x8 __attribute__((ext_vector_type(8)));
typedef float f32x4 __attribute__((ext_vector_type(4)));

__device__ __forceinline__ void gl_lds16(const void* g, void* l) {
    __builtin_amdgcn_global_load_lds((const __attribute__((address_space(1))) unsigned int*)g,
                                     (__attribute__((address_space(3))) unsigned int*)l, 16, 0, 0);
}

// ---------------- fp32 -> bf16 weight conversion ----------------
__global__ void cvt_bf16_kernel(const float* __restrict__ src, bf16* __restrict__ dst, int n) {
    int i = (blockIdx.x * 256 + threadIdx.x) * 4;
    if (i < n) {
        float4 v = *(const float4*)(src + i);
        bf16x4 o;
        o[0] = (bf16)v.x; o[1] = (bf16)v.y; o[2] = (bf16)v.z; o[3] = (bf16)v.w;
        *(bf16x4*)(dst + i) = o;
    }
}

// ---------------- LayerNorm (one wave per row of 512) ----------------
__global__ void ln_kernel(const float* __restrict__ X, const float* __restrict__ gam,
                          const float* __restrict__ bet, bf16* __restrict__ out) {
    int w = threadIdx.x >> 6, l = threadIdx.x & 63;
    long row = (long)blockIdx.x * 4 + w;
    const float* xp = X + row * DIM + l * 8;
    float4 a = *(const float4*)xp;
    float4 b = *(const float4*)(xp + 4);
    float s1 = a.x + a.y + a.z + a.w + b.x + b.y + b.z + b.w;
    float s2 = a.x*a.x + a.y*a.y + a.z*a.z + a.w*a.w + b.x*b.x + b.y*b.y + b.z*b.z + b.w*b.w;
#pragma unroll
    for (int off = 32; off; off >>= 1) { s1 += __shfl_xor(s1, off); s2 += __shfl_xor(s2, off); }
    float mean = s1 * (1.f / 512.f);
    float var  = s2 * (1.f / 512.f) - mean * mean;
    float rstd = rsqrtf(var + 1e-5f);
    float4 g0 = *(const float4*)(gam + l * 8), g1 = *(const float4*)(gam + l * 8 + 4);
    float4 b0 = *(const float4*)(bet + l * 8), b1 = *(const float4*)(bet + l * 8 + 4);
    bf16x8 o;
    o[0] = (bf16)((a.x - mean) * rstd * g0.x + b0.x);
    o[1] = (bf16)((a.y - mean) * rstd * g0.y + b0.y);
    o[2] = (bf16)((a.z - mean) * rstd * g0.z + b0.z);
    o[3] = (bf16)((a.w - mean) * rstd * g0.w + b0.w);
    o[4] = (bf16)((b.x - mean) * rstd * g1.x + b1.x);
    o[5] = (bf16)((b.y - mean) * rstd * g1.y + b1.y);
    o[6] = (bf16)((b.z - mean) * rstd * g1.z + b1.z);
    o[7] = (bf16)((b.w - mean) * rstd * g1.w + b1.w);
    *(bf16x8*)(out + row * DIM + l * 8) = o;
}

// ---------------- GEMM: out[M,N] = A[M,K] * W[N,K]^T (+ epilogue) ----------------
// EPI 0: scatter to QKV bf16 bufs [3][B][H][N][Dh]
// EPI 1: + bias + resid -> fp32 (proj / fc2)
// EPI 2: + bias, exact GELU -> bf16 (fc1)
template<int EPI>
__global__ void gemm_bt(const bf16* __restrict__ A, const bf16* __restrict__ W,
                        const float* __restrict__ bias, const float* resid,
                        void* outp, int M, int N, int K) {
    __shared__ bf16 As[128 * 64];
    __shared__ bf16 Bs[128 * 64];
    int t = threadIdx.x, w = t >> 6, l = t & 63;
    int wr = w >> 1, wc = w & 1, g = l >> 4, c = l & 15;
    long arow0 = (long)blockIdx.y * 128, bcol0 = (long)blockIdx.x * 128;
    f32x4 acc[4][4] = {};
    int lrow = l >> 3, lcol = (l & 7) * 8;
    const bf16* Ab = A + (arow0 + lrow) * (long)K + lcol;
    const bf16* Wb = W + (bcol0 + lrow) * (long)K + lcol;
    for (int k0 = 0; k0 < K; k0 += 64) {
#pragma unroll
        for (int q = 0; q < 4; ++q) {
            int ci = w * 4 + q;
            gl_lds16(Ab + (long)ci * 8 * K + k0, &As[ci * 512]);
            gl_lds16(Wb + (long)ci * 8 * K + k0, &Bs[ci * 512]);
        }
        __syncthreads();
#pragma unroll
        for (int kk = 0; kk < 2; ++kk) {
            bf16x8 af[4], bfr[4];
#pragma unroll
            for (int m = 0; m < 4; ++m) af[m]  = *(const bf16x8*)&As[(wr * 64 + m * 16 + c) * 64 + kk * 32 + g * 8];
#pragma unroll
            for (int n = 0; n < 4; ++n) bfr[n] = *(const bf16x8*)&Bs[(wc * 64 + n * 16 + c) * 64 + kk * 32 + g * 8];
#pragma unroll
            for (int m = 0; m < 4; ++m)
#pragma unroll
                for (int n = 0; n < 4; ++n)
                    acc[m][n] = __builtin_amdgcn_mfma_f32_16x16x32_bf16(af[m], bfr[n], acc[m][n], 0, 0, 0);
        }
        __syncthreads();
    }
#pragma unroll
    for (int m = 0; m < 4; ++m)
#pragma unroll
        for (int n = 0; n < 4; ++n) {
            long row = arow0 + wr * 64 + m * 16 + g * 4;
            long col = bcol0 + wc * 64 + n * 16 + c;
#pragma unroll
            for (int r = 0; r < 4; ++r) {
                float v = acc[m][n][r];
                long rr = row + r;
                if constexpr (EPI == 0) {
                    int o = (int)col;
                    int s = o >> 9, hh = (o >> 6) & 7, d = o & 63;
                    int b = (int)(rr >> 11), nn = (int)(rr & 2047);
                    ((bf16*)outp)[(((long)(s * NB + b) * HEADS + hh) * NT + nn) * DH + d] = (bf16)v;
                } else if constexpr (EPI == 1) {
                    ((float*)outp)[rr * N + col] = v + bias[col] + resid[rr * N + col];
                } else {
                    float u = v + bias[col];
                    float ge = 0.5f * u * (1.f + erff(u * 0.70710678118654752f));
                    ((bf16*)outp)[rr * N + col] = (bf16)ge;
                }
            }
        }
}

// ---------------- Flash attention (swapped QK^T, 64-key tiles) ----------------
__global__ void attn_kernel(const bf16* __restrict__ qkv, bf16* __restrict__ O) {
    __shared__ bf16 Ks[64 * 64];
    __shared__ bf16 Vt[64 * 64];
    int t = threadIdx.x, w = t >> 6, l = t & 63;
    int g = l >> 4, c = l & 15;
    int qt = blockIdx.x, bh = blockIdx.y;
    long headoff = (long)bh * (NT * DH);
    const bf16* Qb = qkv + headoff;
    const bf16* Kb = qkv + (long)(NB * HEADS) * (NT * DH) + headoff;
    const bf16* Vb = qkv + (long)2 * (NB * HEADS) * (NT * DH) + headoff;
    int q0 = qt * 64 + w * 16;
    bf16x8 qf[2];
    qf[0] = *(const bf16x8*)(Qb + (long)(q0 + c) * DH + g * 8);
    qf[1] = *(const bf16x8*)(Qb + (long)(q0 + c) * DH + 32 + g * 8);
    f32x4 oacc[4] = {};
    float mrun = -__builtin_inff(), lrun = 0.f;
    const float scale = 0.125f;
    int skey = t >> 3, sdh = (t & 7) * 8;   // K staging
    int vdh = t & 63, vkg = t >> 6;          // V^T staging

    for (int kt = 0; kt < NT / 64; ++kt) {
        int key0 = kt * 64;
#pragma unroll
        for (int p = 0; p < 2; ++p) {
            int key = p * 32 + skey;
            bf16x8 kv = *(const bf16x8*)(Kb + (long)(key0 + key) * DH + sdh);
            *(bf16x8*)&Ks[(key * 64 + sdh) ^ ((key & 7) << 3)] = kv;
        }
        {
            const bf16* vp = Vb + (long)(key0 + vkg * 16) * DH + vdh;
            alignas(16) bf16 tmp[16];
#pragma unroll
            for (int i = 0; i < 16; ++i) tmp[i] = vp[(long)i * DH];
            *(bf16x8*)&Vt[(vdh * 64 + vkg * 16) ^ ((vdh & 7) << 3)]     = *(bf16x8*)&tmp[0];
            *(bf16x8*)&Vt[(vdh * 64 + vkg * 16 + 8) ^ ((vdh & 7) << 3)] = *(bf16x8*)&tmp[8];
        }
        __syncthreads();
        // S^T = K * Q^T : rows=keys, cols=q
        f32x4 st[4] = {};
#pragma unroll
        for (int kk = 0; kk < 2; ++kk)
#pragma unroll
            for (int kc = 0; kc < 4; ++kc) {
                int key = kc * 16 + c;
                bf16x8 kf = *(const bf16x8*)&Ks[(key * 64 + kk * 32 + g * 8) ^ ((key & 7) << 3)];
                st[kc] = __builtin_amdgcn_mfma_f32_16x16x32_bf16(kf, qf[kk], st[kc], 0, 0, 0);
            }
        // online softmax over keys (rows); per-lane column q = c
        float pv[4][4];
        float mt = -__builtin_inff();
#pragma unroll
        for (int kc = 0; kc < 4; ++kc)
#pragma unroll
            for (int r = 0; r < 4; ++r) { float sv = st[kc][r] * scale; pv[kc][r] = sv; mt = fmaxf(mt, sv); }
        mt = fmaxf(mt, __shfl_xor(mt, 16));
        mt = fmaxf(mt, __shfl_xor(mt, 32));
        float mnew = fmaxf(mrun, mt);
        float fr = __expf(mrun - mnew);
        float ssum = 0.f;
#pragma unroll
        for (int kc = 0; kc < 4; ++kc)
#pragma unroll
            for (int r = 0; r < 4; ++r) { float p = __expf(pv[kc][r] - mnew); pv[kc][r] = p; ssum += p; }
        ssum += __shfl_xor(ssum, 16);
        ssum += __shfl_xor(ssum, 32);
        lrun = lrun * fr + ssum;
        mrun = mnew;
#pragma unroll
        for (int dc = 0; dc < 4; ++dc) oacc[dc] *= fr;
        // pack P^T fragments (in-register, layout-exact for B operand)
        bf16x8 pf[2];
#pragma unroll
        for (int ks = 0; ks < 2; ++ks)
#pragma unroll
            for (int j = 0; j < 8; ++j) pf[ks][j] = (bf16)pv[2 * ks + (j >> 2)][j & 3];
        // O^T += V^T * P^T
#pragma unroll
        for (int dc = 0; dc < 4; ++dc) {
            int dh = dc * 16 + c;
            int hwb = dh * 64, sw = (dh & 7) << 3;
#pragma unroll
            for (int ks = 0; ks < 2; ++ks) {
                bf16x4 v0 = *(const bf16x4*)&Vt[(hwb + ks * 32 + g * 4) ^ sw];
                bf16x4 v1 = *(const bf16x4*)&Vt[(hwb + ks * 32 + 16 + g * 4) ^ sw];
                bf16x8 vf = __builtin_shufflevector(v0, v1, 0, 1, 2, 3, 4, 5, 6, 7);
                oacc[dc] = __builtin_amdgcn_mfma_f32_16x16x32_bf16(vf, pf[ks], oacc[dc], 0, 0, 0);
            }
        }
        __syncthreads();
    }
    // epilogue: O^T -> LDS transpose -> coalesced global store
    float inv = 1.f / lrun;
    bf16* ol = &Ks[w * 1024];
#pragma unroll
    for (int dc = 0; dc < 4; ++dc)
#pragma unroll
        for (int r = 0; r < 4; ++r)
            ol[c * 64 + dc * 16 + g * 4 + r] = (bf16)(oacc[dc][r] * inv);
    int qq = l >> 2, dh0 = (l & 3) * 16;
    int b = bh >> 3, hh = bh & 7;
    bf16x8 r0 = *(const bf16x8*)&ol[qq * 64 + dh0];
    bf16x8 r1 = *(const bf16x8*)&ol[qq * 64 + dh0 + 8];
    long tok = (long)b * NT + q0 + qq;
    *(bf16x8*)(O + tok * DIM + hh * 64 + dh0) = r0;
    *(bf16x8*)(O + tok * DIM + hh * 64 + dh0 + 8) = r1;
}

extern "C" void kernel_launch(void* const* d_in, const int* in_sizes, int n_in,
                              void* d_out, int out_size, void* d_ws, size_t ws_size,
                              hipStream_t stream) {
    const float* x      = (const float*)d_in[0];
    const float* ln1_w  = (const float*)d_in[1];
    const float* ln1_b  = (const float*)d_in[2];
    const float* qkv_w  = (const float*)d_in[3];
    const float* proj_w = (const float*)d_in[4];
    const float* proj_b = (const float*)d_in[5];
    const float* ln2_w  = (const float*)d_in[6];
    const float* ln2_b  = (const float*)d_in[7];
    const float* fc1_w  = (const float*)d_in[8];
    const float* fc1_b  = (const float*)d_in[9];
    const float* fc2_w  = (const float*)d_in[10];
    const float* fc2_b  = (const float*)d_in[11];
    float* X = (float*)d_out;   // residual stream lives in d_out

    char* ws = (char*)d_ws;
    bf16* h_bf   = (bf16*)(ws);                                  // 8 MB
    bf16* scr_bf = (bf16*)(ws + (size_t)(8  << 20));             // 32 MB (qkv | gelu)
    bf16* o_bf   = (bf16*)(ws + (size_t)(40 << 20));             // 8 MB
    bf16* w_qkv  = (bf16*)(ws + (size_t)(48 << 20));
    bf16* w_proj = w_qkv  + (size_t)4 * 1536 * 512;
    bf16* w_fc1  = w_proj + (size_t)4 * 512 * 512;
    bf16* w_fc2  = w_fc1  + (size_t)4 * 2048 * 512;

    // convert weights to bf16
    {
        int n;
        n = 4 * 1536 * 512; cvt_bf16_kernel<<<n / 1024, 256, 0, stream>>>(qkv_w,  w_qkv,  n);
        n = 4 * 512 * 512;  cvt_bf16_kernel<<<n / 1024, 256, 0, stream>>>(proj_w, w_proj, n);
        n = 4 * 2048 * 512; cvt_bf16_kernel<<<n / 1024, 256, 0, stream>>>(fc1_w,  w_fc1,  n);
        n = 4 * 512 * 2048; cvt_bf16_kernel<<<n / 1024, 256, 0, stream>>>(fc2_w,  w_fc2,  n);
    }
    hipMemcpyAsync(X, x, (size_t)M_TOK * DIM * sizeof(float), hipMemcpyDeviceToDevice, stream);

    for (int i = 0; i < 4; ++i) {
        ln_kernel<<<M_TOK / 4, 256, 0, stream>>>(X, ln1_w + i * 512, ln1_b + i * 512, h_bf);
        gemm_bt<0><<<dim3(12, 64), 256, 0, stream>>>(h_bf, w_qkv + (size_t)i * 1536 * 512,
                                                     nullptr, nullptr, scr_bf, M_TOK, 1536, 512);
        attn_kernel<<<dim3(32, 32), 256, 0, stream>>>(scr_bf, o_bf);
        gemm_bt<1><<<dim3(4, 64), 256, 0, stream>>>(o_bf, w_proj + (size_t)i * 512 * 512,
                                                    proj_b + i * 512, X, X, M_TOK, 512, 512);
        ln_kernel<<<M_TOK / 4, 256, 0, stream>>>(X, ln2_w + i * 512, ln2_b + i * 512, h_bf);
        gemm_bt<2><<<dim3(16, 64), 256, 0, stream>>>(h_bf, w_fc1 + (size_t)i * 2048 * 512,
                                                     fc1_b + i * 2048, nullptr, scr_bf, M_TOK, 2048, 512);
        gemm_bt<1><<<dim3(4, 64), 256, 0, stream>>>(scr_bf, w_fc2 + (size_t)i * 512 * 2048,
                                                    fc2_b + i * 512, X, X, M_TOK, 512, 2048);
    }
}

// Round 2
// 857.798 us; speedup vs baseline: 1.0060x; 1.0060x over previous
//
#include <hip/hip_runtime.h>
#include <hip/hip_bf16.h>
#include <math.h>

#define NB 4
#define HEADS 8
#define DIM 512
#define MLP 2048
#define NT 2048
#define DH 64
#define M_TOK (NB*NT)

typedef __bf16 bf16;
typedef __bf16 bf16x4 __attribute__((ext_vector_type(4)));
typedef __bf16 bf16x8 __attribute__((ext_vector_type(8)));
typedef float f32x4 __attribute__((ext_vector_type(4)));

__device__ __forceinline__ void gl_lds16(const void* g, void* l) {
    __builtin_amdgcn_global_load_lds((const __attribute__((address_space(1))) unsigned int*)g,
                                     (__attribute__((address_space(3))) unsigned int*)l, 16, 0, 0);
}

#define BARRIER() do { __builtin_amdgcn_s_barrier(); asm volatile("" ::: "memory"); } while(0)
#define WAIT_VM4() asm volatile("s_waitcnt vmcnt(4)" ::: "memory")
#define WAIT_VM0() asm volatile("s_waitcnt vmcnt(0)" ::: "memory")

// ---------------- fp32 -> bf16 weight conversion ----------------
__global__ void cvt_bf16_kernel(const float* __restrict__ src, bf16* __restrict__ dst, int n) {
    int i = (blockIdx.x * 256 + threadIdx.x) * 4;
    if (i < n) {
        float4 v = *(const float4*)(src + i);
        bf16x4 o;
        o[0] = (bf16)v.x; o[1] = (bf16)v.y; o[2] = (bf16)v.z; o[3] = (bf16)v.w;
        *(bf16x4*)(dst + i) = o;
    }
}

// ---------------- LayerNorm (one wave per row of 512) ----------------
__global__ void ln_kernel(const float* __restrict__ X, const float* __restrict__ gam,
                          const float* __restrict__ bet, bf16* __restrict__ out) {
    int w = threadIdx.x >> 6, l = threadIdx.x & 63;
    long row = (long)blockIdx.x * 4 + w;
    const float* xp = X + row * DIM + l * 8;
    float4 a = *(const float4*)xp;
    float4 b = *(const float4*)(xp + 4);
    float s1 = a.x + a.y + a.z + a.w + b.x + b.y + b.z + b.w;
    float s2 = a.x*a.x + a.y*a.y + a.z*a.z + a.w*a.w + b.x*b.x + b.y*b.y + b.z*b.z + b.w*b.w;
#pragma unroll
    for (int off = 32; off; off >>= 1) { s1 += __shfl_xor(s1, off); s2 += __shfl_xor(s2, off); }
    float mean = s1 * (1.f / 512.f);
    float var  = s2 * (1.f / 512.f) - mean * mean;
    float rstd = rsqrtf(var + 1e-5f);
    float4 g0 = *(const float4*)(gam + l * 8), g1 = *(const float4*)(gam + l * 8 + 4);
    float4 b0 = *(const float4*)(bet + l * 8), b1 = *(const float4*)(bet + l * 8 + 4);
    bf16x8 o;
    o[0] = (bf16)((a.x - mean) * rstd * g0.x + b0.x);
    o[1] = (bf16)((a.y - mean) * rstd * g0.y + b0.y);
    o[2] = (bf16)((a.z - mean) * rstd * g0.z + b0.z);
    o[3] = (bf16)((a.w - mean) * rstd * g0.w + b0.w);
    o[4] = (bf16)((b.x - mean) * rstd * g1.x + b1.x);
    o[5] = (bf16)((b.y - mean) * rstd * g1.y + b1.y);
    o[6] = (bf16)((b.z - mean) * rstd * g1.z + b1.z);
    o[7] = (bf16)((b.w - mean) * rstd * g1.w + b1.w);
    *(bf16x8*)(out + row * DIM + l * 8) = o;
}

// ================= 256x256 8-phase GEMM, K=512 fixed =================
// out[M,N] = A[M,K=512] * W[N,512]^T, EPI 0: QKV scatter, EPI 2: +bias GELU->bf16
// 8 waves (2M x 4N), wave tile 128x64, BK=64, double-buffered LDS (128 KiB),
// XOR swizzle (colbyte ^= (row&7)<<4) via pre-swizzled global source.
#define KDIM 512

#define LOADA(AF, B_, MQ) do { \
  _Pragma("unroll") for (int mi_ = 0; mi_ < 4; ++mi_) \
  _Pragma("unroll") for (int kk_ = 0; kk_ < 2; ++kk_) { \
    int row_ = wr * 128 + ((MQ) * 4 + mi_) * 16 + c; \
    AF[mi_][kk_] = *(const bf16x8*)&Abuf[B_][row_ * 64 + (((kk_ * 64 + g * 16) ^ sw) >> 1)]; \
  } } while (0)

#define LOADB(BF, B_, NQ) do { \
  _Pragma("unroll") for (int ni_ = 0; ni_ < 2; ++ni_) \
  _Pragma("unroll") for (int kk_ = 0; kk_ < 2; ++kk_) { \
    int row_ = wc * 64 + ((NQ) * 2 + ni_) * 16 + c; \
    BF[ni_][kk_] = *(const bf16x8*)&Bbuf[B_][row_ * 64 + (((kk_ * 64 + g * 16) ^ sw) >> 1)]; \
  } } while (0)

#define MFMA16(AF, BF, MQ, NQ) do { \
  __builtin_amdgcn_s_setprio(1); \
  _Pragma("unroll") for (int mi_ = 0; mi_ < 4; ++mi_) \
  _Pragma("unroll") for (int ni_ = 0; ni_ < 2; ++ni_) \
  _Pragma("unroll") for (int kk_ = 0; kk_ < 2; ++kk_) \
    acc[(MQ)*4+mi_][(NQ)*2+ni_] = __builtin_amdgcn_mfma_f32_16x16x32_bf16( \
        AF[mi_][kk_], BF[ni_][kk_], acc[(MQ)*4+mi_][(NQ)*2+ni_], 0, 0, 0); \
  __builtin_amdgcn_s_setprio(0); \
} while (0)

// stage region A_mq of K-tile J into Abuf[J&1] (2 x gl_lds per thread, 16KB)
#define STAGE_A(J_, MQ) do { int j_ = (J_); if (j_ < nkt) { \
  bf16* db_ = Abuf[j_ & 1]; const bf16* sb_ = Aptr + (size_t)j_ * 64 + coloff; \
  _Pragma("unroll") for (int q_ = 0; q_ < 2; ++q_) { \
    int rpl_ = (MQ) * 64 + q_ * 128 + r0; \
    int rwb_ = (MQ) * 64 + q_ * 128 + (w << 3); \
    gl_lds16(sb_ + (size_t)(arow0 + rpl_) * KDIM, db_ + rwb_ * 64); \
  } } } while (0)

#define STAGE_B(J_, NQ) do { int j_ = (J_); if (j_ < nkt) { \
  bf16* db_ = Bbuf[j_ & 1]; const bf16* sb_ = Wptr + (size_t)j_ * 64 + coloff; \
  _Pragma("unroll") for (int q_ = 0; q_ < 2; ++q_) { \
    int rpl_ = q_ * 128 + ((r0 >> 5) << 6) + (NQ) * 32 + (r0 & 31); \
    int rwb_ = q_ * 128 + (((w << 3) >> 5) << 6) + (NQ) * 32 + ((w << 3) & 31); \
    gl_lds16(sb_ + (size_t)(bcol0 + rpl_) * KDIM, db_ + rwb_ * 64); \
  } } } while (0)

template<int EPI>
__global__ __launch_bounds__(512, 2) void gemm256(const bf16* __restrict__ Aptr,
                                                  const bf16* __restrict__ Wptr,
                                                  const float* __restrict__ bias,
                                                  void* outp, int M, int N) {
    __shared__ bf16 Abuf[2][256 * 64];
    __shared__ bf16 Bbuf[2][256 * 64];
    const int t = threadIdx.x, w = t >> 6, l = t & 63;
    const int wr = w >> 2, wc = w & 3, g = l >> 4, c = l & 15;
    const int sw = (c & 7) << 4;                      // read-side swizzle (bytes)
    const int r0 = (w << 3) + (l >> 3);               // staging row core
    const int coloff = ((l & 7) ^ (l >> 3)) << 3;     // pre-swizzled source col (bf16)

    // XCD-bijective block swizzle
    int nwg = gridDim.x;
    int bid = blockIdx.x;
    int q8 = nwg >> 3, r8 = nwg & 7;
    int xcd = bid & 7, rank = bid >> 3;
    int swz = (xcd < r8) ? xcd * (q8 + 1) + rank : r8 * (q8 + 1) + (xcd - r8) * q8 + rank;
    int tiles_n = N >> 8;
    long arow0 = (long)(swz / tiles_n) * 256;
    long bcol0 = (long)(swz % tiles_n) * 256;

    const int nkt = KDIM / 64;        // 8
    const int niter = nkt / 2;        // 4
    f32x4 acc[8][4] = {};
    bf16x8 af[4][2], bn0[2][2], bn1[2][2];

    // prologue: kt0 all regions + kt1 {A_m0, B_n0}  (12 loads)
    STAGE_A(0, 0); STAGE_B(0, 0); STAGE_A(0, 1); STAGE_B(0, 1);
    STAGE_A(1, 0); STAGE_B(1, 0);

#pragma unroll 1
    for (int tt = 0; tt < niter; ++tt) {
        const int J0 = 2 * tt, J1 = 2 * tt + 1;
        const bool last = (tt == niter - 1);
        // ---- phase 0: J0 Q(m0,n0) ----
        WAIT_VM4(); BARRIER();
        LOADA(af, 0, 0); LOADB(bn0, 0, 0);
        STAGE_A(J0 + 1, 1);
        MFMA16(af, bn0, 0, 0);
        BARRIER();
        // ---- phase 1: J0 Q(m0,n1) ----
        LOADB(bn1, 0, 1);
        STAGE_B(J0 + 1, 1);
        MFMA16(af, bn1, 0, 1);
        BARRIER();
        // ---- phase 2: J0 Q(m1,n0) ----
        LOADA(af, 0, 1);
        STAGE_A(J0 + 2, 0);
        MFMA16(af, bn0, 1, 0);
        BARRIER();
        // ---- phase 3: J0 Q(m1,n1) ----
        STAGE_B(J0 + 2, 0);
        MFMA16(af, bn1, 1, 1);
        BARRIER();
        // ---- phase 4: J1 Q(m0,n0) ----
        if (last) { WAIT_VM0(); } else { WAIT_VM4(); }
        BARRIER();
        LOADA(af, 1, 0); LOADB(bn0, 1, 0);
        STAGE_A(J1 + 1, 1);
        MFMA16(af, bn0, 0, 0);
        BARRIER();
        // ---- phase 5: J1 Q(m0,n1) ----
        LOADB(bn1, 1, 1);
        STAGE_B(J1 + 1, 1);
        MFMA16(af, bn1, 0, 1);
        BARRIER();
        // ---- phase 6: J1 Q(m1,n0) ----
        LOADA(af, 1, 1);
        STAGE_A(J1 + 2, 0);
        MFMA16(af, bn0, 1, 0);
        BARRIER();
        // ---- phase 7: J1 Q(m1,n1) ----
        STAGE_B(J1 + 2, 0);
        MFMA16(af, bn1, 1, 1);
        BARRIER();
    }

    // epilogue
#pragma unroll
    for (int m = 0; m < 8; ++m)
#pragma unroll
        for (int n = 0; n < 4; ++n) {
            long row = arow0 + wr * 128 + m * 16 + g * 4;
            long col = bcol0 + wc * 64 + n * 16 + c;
#pragma unroll
            for (int r = 0; r < 4; ++r) {
                float v = acc[m][n][r];
                long rr = row + r;
                if constexpr (EPI == 0) {
                    int o = (int)col;
                    int s = o >> 9, hh = (o >> 6) & 7, d = o & 63;
                    int b = (int)(rr >> 11), nn = (int)(rr & 2047);
                    ((bf16*)outp)[(((long)(s * NB + b) * HEADS + hh) * NT + nn) * DH + d] = (bf16)v;
                } else {
                    float u = v + bias[col];
                    float ge = 0.5f * u * (1.f + erff(u * 0.70710678118654752f));
                    ((bf16*)outp)[rr * N + col] = (bf16)ge;
                }
            }
        }
}

// ---------------- 128x128 GEMM (m97 structure) for narrow N ----------------
// EPI 1: + bias + resid -> fp32 (proj / fc2)
__global__ void gemm_bt(const bf16* __restrict__ A, const bf16* __restrict__ W,
                        const float* __restrict__ bias, const float* resid,
                        float* outp, int M, int N, int K) {
    __shared__ bf16 As[128 * 64];
    __shared__ bf16 Bs[128 * 64];
    int t = threadIdx.x, w = t >> 6, l = t & 63;
    int wr = w >> 1, wc = w & 1, g = l >> 4, c = l & 15;
    long arow0 = (long)blockIdx.y * 128, bcol0 = (long)blockIdx.x * 128;
    f32x4 acc[4][4] = {};
    int lrow = l >> 3, lcol = (l & 7) * 8;
    const bf16* Ab = A + (arow0 + lrow) * (long)K + lcol;
    const bf16* Wb = W + (bcol0 + lrow) * (long)K + lcol;
    for (int k0 = 0; k0 < K; k0 += 64) {
#pragma unroll
        for (int q = 0; q < 4; ++q) {
            int ci = w * 4 + q;
            gl_lds16(Ab + (long)ci * 8 * K + k0, &As[ci * 512]);
            gl_lds16(Wb + (long)ci * 8 * K + k0, &Bs[ci * 512]);
        }
        __syncthreads();
#pragma unroll
        for (int kk = 0; kk < 2; ++kk) {
            bf16x8 afv[4], bfr[4];
#pragma unroll
            for (int m = 0; m < 4; ++m) afv[m] = *(const bf16x8*)&As[(wr * 64 + m * 16 + c) * 64 + kk * 32 + g * 8];
#pragma unroll
            for (int n = 0; n < 4; ++n) bfr[n] = *(const bf16x8*)&Bs[(wc * 64 + n * 16 + c) * 64 + kk * 32 + g * 8];
#pragma unroll
            for (int m = 0; m < 4; ++m)
#pragma unroll
                for (int n = 0; n < 4; ++n)
                    acc[m][n] = __builtin_amdgcn_mfma_f32_16x16x32_bf16(afv[m], bfr[n], acc[m][n], 0, 0, 0);
        }
        __syncthreads();
    }
#pragma unroll
    for (int m = 0; m < 4; ++m)
#pragma unroll
        for (int n = 0; n < 4; ++n) {
            long row = arow0 + wr * 64 + m * 16 + g * 4;
            long col = bcol0 + wc * 64 + n * 16 + c;
#pragma unroll
            for (int r = 0; r < 4; ++r) {
                long rr = row + r;
                outp[rr * N + col] = acc[m][n][r] + bias[col] + resid[rr * N + col];
            }
        }
}

// ---------------- Flash attention (swapped QK^T, 64-key tiles) ----------------
__global__ void attn_kernel(const bf16* __restrict__ qkv, bf16* __restrict__ O) {
    __shared__ bf16 Ks[64 * 64];
    __shared__ bf16 Vt[64 * 64];
    int t = threadIdx.x, w = t >> 6, l = t & 63;
    int g = l >> 4, c = l & 15;
    int qt = blockIdx.x, bh = blockIdx.y;
    long headoff = (long)bh * (NT * DH);
    const bf16* Qb = qkv + headoff;
    const bf16* Kb = qkv + (long)(NB * HEADS) * (NT * DH) + headoff;
    const bf16* Vb = qkv + (long)2 * (NB * HEADS) * (NT * DH) + headoff;
    int q0 = qt * 64 + w * 16;
    bf16x8 qf[2];
    qf[0] = *(const bf16x8*)(Qb + (long)(q0 + c) * DH + g * 8);
    qf[1] = *(const bf16x8*)(Qb + (long)(q0 + c) * DH + 32 + g * 8);
    f32x4 oacc[4] = {};
    float mrun = -__builtin_inff(), lrun = 0.f;
    const float scale = 0.125f;
    int skey = t >> 3, sdh = (t & 7) * 8;
    int vdh = t & 63, vkg = t >> 6;

    for (int kt = 0; kt < NT / 64; ++kt) {
        int key0 = kt * 64;
#pragma unroll
        for (int p = 0; p < 2; ++p) {
            int key = p * 32 + skey;
            bf16x8 kv = *(const bf16x8*)(Kb + (long)(key0 + key) * DH + sdh);
            *(bf16x8*)&Ks[(key * 64 + sdh) ^ ((key & 7) << 3)] = kv;
        }
        {
            const bf16* vp = Vb + (long)(key0 + vkg * 16) * DH + vdh;
            alignas(16) bf16 tmp[16];
#pragma unroll
            for (int i = 0; i < 16; ++i) tmp[i] = vp[(long)i * DH];
            *(bf16x8*)&Vt[(vdh * 64 + vkg * 16) ^ ((vdh & 7) << 3)]     = *(bf16x8*)&tmp[0];
            *(bf16x8*)&Vt[(vdh * 64 + vkg * 16 + 8) ^ ((vdh & 7) << 3)] = *(bf16x8*)&tmp[8];
        }
        __syncthreads();
        f32x4 st[4] = {};
#pragma unroll
        for (int kk = 0; kk < 2; ++kk)
#pragma unroll
            for (int kc = 0; kc < 4; ++kc) {
                int key = kc * 16 + c;
                bf16x8 kf = *(const bf16x8*)&Ks[(key * 64 + kk * 32 + g * 8) ^ ((key & 7) << 3)];
                st[kc] = __builtin_amdgcn_mfma_f32_16x16x32_bf16(kf, qf[kk], st[kc], 0, 0, 0);
            }
        float pv[4][4];
        float mt = -__builtin_inff();
#pragma unroll
        for (int kc = 0; kc < 4; ++kc)
#pragma unroll
            for (int r = 0; r < 4; ++r) { float sv = st[kc][r] * scale; pv[kc][r] = sv; mt = fmaxf(mt, sv); }
        mt = fmaxf(mt, __shfl_xor(mt, 16));
        mt = fmaxf(mt, __shfl_xor(mt, 32));
        float mnew = fmaxf(mrun, mt);
        float fr = __expf(mrun - mnew);
        float ssum = 0.f;
#pragma unroll
        for (int kc = 0; kc < 4; ++kc)
#pragma unroll
            for (int r = 0; r < 4; ++r) { float p = __expf(pv[kc][r] - mnew); pv[kc][r] = p; ssum += p; }
        ssum += __shfl_xor(ssum, 16);
        ssum += __shfl_xor(ssum, 32);
        lrun = lrun * fr + ssum;
        mrun = mnew;
#pragma unroll
        for (int dc = 0; dc < 4; ++dc) oacc[dc] *= fr;
        bf16x8 pf[2];
#pragma unroll
        for (int ks = 0; ks < 2; ++ks)
#pragma unroll
            for (int j = 0; j < 8; ++j) pf[ks][j] = (bf16)pv[2 * ks + (j >> 2)][j & 3];
#pragma unroll
        for (int dc = 0; dc < 4; ++dc) {
            int dh = dc * 16 + c;
            int hwb = dh * 64, swv = (dh & 7) << 3;
#pragma unroll
            for (int ks = 0; ks < 2; ++ks) {
                bf16x4 v0 = *(const bf16x4*)&Vt[(hwb + ks * 32 + g * 4) ^ swv];
                bf16x4 v1 = *(const bf16x4*)&Vt[(hwb + ks * 32 + 16 + g * 4) ^ swv];
                bf16x8 vf = __builtin_shufflevector(v0, v1, 0, 1, 2, 3, 4, 5, 6, 7);
                oacc[dc] = __builtin_amdgcn_mfma_f32_16x16x32_bf16(vf, pf[ks], oacc[dc], 0, 0, 0);
            }
        }
        __syncthreads();
    }
    float inv = 1.f / lrun;
    bf16* ol = &Ks[w * 1024];
#pragma unroll
    for (int dc = 0; dc < 4; ++dc)
#pragma unroll
        for (int r = 0; r < 4; ++r)
            ol[c * 64 + dc * 16 + g * 4 + r] = (bf16)(oacc[dc][r] * inv);
    int qq = l >> 2, dh0 = (l & 3) * 16;
    int b = bh >> 3, hh = bh & 7;
    bf16x8 r0 = *(const bf16x8*)&ol[qq * 64 + dh0];
    bf16x8 r1 = *(const bf16x8*)&ol[qq * 64 + dh0 + 8];
    long tok = (long)b * NT + q0 + qq;
    *(bf16x8*)(O + tok * DIM + hh * 64 + dh0) = r0;
    *(bf16x8*)(O + tok * DIM + hh * 64 + dh0 + 8) = r1;
}

extern "C" void kernel_launch(void* const* d_in, const int* in_sizes, int n_in,
                              void* d_out, int out_size, void* d_ws, size_t ws_size,
                              hipStream_t stream) {
    const float* x      = (const float*)d_in[0];
    const float* ln1_w  = (const float*)d_in[1];
    const float* ln1_b  = (const float*)d_in[2];
    const float* qkv_w  = (const float*)d_in[3];
    const float* proj_w = (const float*)d_in[4];
    const float* proj_b = (const float*)d_in[5];
    const float* ln2_w  = (const float*)d_in[6];
    const float* ln2_b  = (const float*)d_in[7];
    const float* fc1_w  = (const float*)d_in[8];
    const float* fc1_b  = (const float*)d_in[9];
    const float* fc2_w  = (const float*)d_in[10];
    const float* fc2_b  = (const float*)d_in[11];
    float* X = (float*)d_out;

    char* ws = (char*)d_ws;
    bf16* h_bf   = (bf16*)(ws);
    bf16* scr_bf = (bf16*)(ws + (size_t)(8  << 20));
    bf16* o_bf   = (bf16*)(ws + (size_t)(40 << 20));
    bf16* w_qkv  = (bf16*)(ws + (size_t)(48 << 20));
    bf16* w_proj = w_qkv  + (size_t)4 * 1536 * 512;
    bf16* w_fc1  = w_proj + (size_t)4 * 512 * 512;
    bf16* w_fc2  = w_fc1  + (size_t)4 * 2048 * 512;

    {
        int n;
        n = 4 * 1536 * 512; cvt_bf16_kernel<<<n / 1024, 256, 0, stream>>>(qkv_w,  w_qkv,  n);
        n = 4 * 512 * 512;  cvt_bf16_kernel<<<n / 1024, 256, 0, stream>>>(proj_w, w_proj, n);
        n = 4 * 2048 * 512; cvt_bf16_kernel<<<n / 1024, 256, 0, stream>>>(fc1_w,  w_fc1,  n);
        n = 4 * 512 * 2048; cvt_bf16_kernel<<<n / 1024, 256, 0, stream>>>(fc2_w,  w_fc2,  n);
    }
    hipMemcpyAsync(X, x, (size_t)M_TOK * DIM * sizeof(float), hipMemcpyDeviceToDevice, stream);

    for (int i = 0; i < 4; ++i) {
        ln_kernel<<<M_TOK / 4, 256, 0, stream>>>(X, ln1_w + i * 512, ln1_b + i * 512, h_bf);
        gemm256<0><<<(M_TOK / 256) * (1536 / 256), 512, 0, stream>>>(
            h_bf, w_qkv + (size_t)i * 1536 * 512, nullptr, scr_bf, M_TOK, 1536);
        attn_kernel<<<dim3(32, 32), 256, 0, stream>>>(scr_bf, o_bf);
        gemm_bt<<<dim3(4, 64), 256, 0, stream>>>(o_bf, w_proj + (size_t)i * 512 * 512,
                                                 proj_b + i * 512, X, X, M_TOK, 512, 512);
        ln_kernel<<<M_TOK / 4, 256, 0, stream>>>(X, ln2_w + i * 512, ln2_b + i * 512, h_bf);
        gemm256<2><<<(M_TOK / 256) * (2048 / 256), 512, 0, stream>>>(
            h_bf, w_fc1 + (size_t)i * 2048 * 512, fc1_b + i * 2048, scr_bf, M_TOK, 2048);
        gemm_bt<<<dim3(4, 64), 256, 0, stream>>>(scr_bf, w_fc2 + (size_t)i * 512 * 2048,
                                                 fc2_b + i * 512, X, X, M_TOK, 512, 2048);
    }
}